// Round 4
// baseline (319.823 us; speedup 1.0000x reference)
//
#include <hip/hip_runtime.h>
#include <hip/hip_bf16.h>
#include <math.h>

#define QDIM 64
#define KDIM 2
#define NDIM 32
#define MDIM 64
#define EDIM 256
#define DDIM 1024
#define RDIM 200
#define SDIM 8192
#define GCOUNT (QDIM * KDIM * NDIM)  // 4096 groups

typedef short short8_t __attribute__((ext_vector_type(8)));
typedef float f32x4 __attribute__((ext_vector_type(4)));

// tanh(x) = 1 - 2/(1+e^{2x}); saturates correctly, ~1ulp rcp error.
__device__ __forceinline__ float tanh_c(float x) {
    float e = __expf(2.0f * x);
    return 1.0f - 2.0f * __builtin_amdgcn_rcpf(1.0f + e);
}

__device__ __forceinline__ uint32_t f2bf(float f) {  // fp32 -> bf16 bits (RNE)
    uint32_t u = __float_as_uint(f);
    return (u + 0x7fffu + ((u >> 16) & 1u)) >> 16;
}
__device__ __forceinline__ float bf2f(unsigned short h) {
    return __uint_as_float(((uint32_t)h) << 16);
}

// ---------------- fused prologue ----------------
// [0,2048): copy hs->out   [2048,2176): pack Wn   [2176,2432): gq
// [2432,2496): rel_prob    [2496,3520): nv scan + bucket count
__global__ __launch_bounds__(256) void prologue_kernel(
    const float* __restrict__ hs, float* __restrict__ out,
    const float* __restrict__ Wn, short* __restrict__ wnpk,
    const int* __restrict__ gnn_idx, const float* __restrict__ Wq,
    const float* __restrict__ bq, float* __restrict__ gqo,
    const int* __restrict__ rel_idx, const float* __restrict__ Wc,
    const float* __restrict__ bc, float* __restrict__ rel_prob,
    const float* __restrict__ nodes, int* __restrict__ nvarr,
    int* __restrict__ bkt) {
    const int b = blockIdx.x, t = threadIdx.x;
    __shared__ float row[DDIM];
    __shared__ float arr[256];

    if (b < 2048) {  // copy 32MB
        const float4* src = (const float4*)hs;
        float4* dst = (float4*)out;
        int i = b * 256 + t;
#pragma unroll
        for (int r = 0; r < 4; ++r) dst[i + r * 524288] = src[i + r * 524288];
    } else if (b < 2176) {  // pack Wn -> bf16 B-fragments
        int tid = (b - 2048) * 256 + t;
        int lane = tid & 63, ks = (tid >> 6) & 7, ntg = tid >> 9;
        int low = lane & 15, hi = lane >> 4;
        short8_t o;
#pragma unroll
        for (int j = 0; j < 8; ++j) {
            int k = ks * 32 + hi * 8 + j;
            int d = ntg * 16 + low;
            o[j] = (short)f2bf(Wn[(size_t)k * DDIM + d]);
        }
        *(short8_t*)(wnpk + (size_t)tid * 8) = o;
    } else if (b < 2432) {  // gq
        int bb = b - 2176;
        int q = bb >> 2, seg = bb & 3;
        const float* src = hs + (size_t)gnn_idx[q] * DDIM;
        for (int i = t; i < DDIM; i += 256) row[i] = src[i];
        __syncthreads();
        int d = seg * 256 + t;
        float a = bq[d];
#pragma unroll 8
        for (int k = 0; k < DDIM; ++k) a += row[k] * Wq[(size_t)k * DDIM + d];
        gqo[(size_t)q * DDIM + d] = tanh_c(a);
    } else if (b < 2496) {  // rel_prob
        int q = b - 2432;
        const float* src = hs + (size_t)rel_idx[q] * DDIM;
        for (int i = t; i < DDIM; i += 256) row[i] = src[i];
        __syncthreads();
        float lg = -INFINITY;
        if (t < RDIM) {
            float a = bc[t];
            for (int k = 0; k < DDIM; ++k) a += row[k] * Wc[(size_t)k * RDIM + t];
            lg = a;
        }
        arr[t] = lg;
        __syncthreads();
        for (int s = 128; s > 0; s >>= 1) {
            if (t < s) arr[t] = fmaxf(arr[t], arr[t + s]);
            __syncthreads();
        }
        float mx = arr[0];
        __syncthreads();
        float ex = (t < RDIM) ? __expf(lg - mx) : 0.0f;
        arr[t] = ex;
        __syncthreads();
        for (int s = 128; s > 0; s >>= 1) {
            if (t < s) arr[t] += arr[t + s];
            __syncthreads();
        }
        float sm = arr[0];
        if (t < RDIM) rel_prob[q * RDIM + t] = ex / sm;
    } else {  // nv scan: wave per group + bucket count
        int g = (b - 2496) * 4 + (t >> 6);
        int lane = t & 63;
        float f0 = nodes[(size_t)g * (MDIM * EDIM) + (size_t)lane * EDIM];
        unsigned long long mk = __ballot(f0 != 0.0f);
        if (lane == 0) {
            int nv = __popcll(mk);
            nvarr[g] = nv;
            int mt = (nv + 15) >> 4;
            if (mt < 1) mt = 1;
            atomicAdd(&bkt[mt - 1], 1);
        }
    }
}

// scatter: glist grouped by MT bucket (order within bucket is irrelevant)
__global__ __launch_bounds__(256) void scatter_kernel(const int* __restrict__ nvarr,
                                                      int* __restrict__ bkt,
                                                      int* __restrict__ glist) {
    int g = blockIdx.x * 256 + threadIdx.x;  // 0..4095
    int nv = nvarr[g];
    int mt = (nv + 15) >> 4;
    if (mt < 1) mt = 1;
    int base = 0;
#pragma unroll
    for (int k = 0; k < 3; ++k)
        if (k < mt - 1) base += bkt[k];
    int pos = base + atomicAdd(&bkt[4 + (mt - 1)], 1);
    glist[pos] = g | (mt << 16);
}

// ---------------- phase1: wave-per-group ----------------
#define WREG 9216  // 8KB stage buffer + 1KB scratch per wave

template <int MT>
__device__ __forceinline__ void wave_body(
    char* ldsw, int g, int q, const float* __restrict__ nodes,
    const short* __restrict__ wnpk, const float* __restrict__ bn,
    const float* __restrict__ gq, const float* __restrict__ rel_prob,
    const int* __restrict__ prob_idx, float* __restrict__ gvec,
    float* __restrict__ gden, float* __restrict__ gmx) {
    const int lane = threadIdx.x & 63;
    const int low = lane & 15, hi = lane >> 4;
    constexpr int NS = MT * 16, TAIL = 64 - NS;

    // ---- stage + hoist A fragments (wave-private LDS, no barriers) ----
    short8_t af[MT][8];
    {
        const float4* src = (const float4*)(nodes + (size_t)g * (MDIM * EDIM));
#pragma unroll
        for (int mt = 0; mt < MT; ++mt) {
#pragma unroll
            for (int i = 0; i < 16; ++i) {
                int idx4 = i * 64 + lane;            // 1024 float4 = 16 rows x 256e
                float4 v = src[mt * 1024 + idx4];
                int r = idx4 >> 6, c4 = idx4 & 63;   // local row, float4-col
                int off = (r * 512 + c4 * 8) ^ ((r & 7) << 4);
                uint32_t w0 = f2bf(v.x) | (f2bf(v.y) << 16);
                uint32_t w1 = f2bf(v.z) | (f2bf(v.w) << 16);
                *(uint2*)(ldsw + off) = make_uint2(w0, w1);
            }
            asm volatile("s_waitcnt lgkmcnt(0)" ::: "memory");
#pragma unroll
            for (int ks = 0; ks < 8; ++ks) {
                int off = (low * 512 + ks * 64 + hi * 16) ^ ((low & 7) << 4);
                af[mt][ks] = *(const short8_t*)(ldsw + off);
            }
            asm volatile("s_waitcnt lgkmcnt(0)" ::: "memory");  // reads done before next overwrite
        }
    }

    // ---- main loop: all 64 d-tiles in this wave (B shared across waves via L1) ----
    float dacc[MT][4];
#pragma unroll
    for (int mt = 0; mt < MT; ++mt)
#pragma unroll
        for (int jj = 0; jj < 4; ++jj) dacc[mt][jj] = 0.f;
    float cpart = 0.f;
    const float* gqrow = gq + (size_t)q * DDIM;
    const short8_t* bb = (const short8_t*)wnpk + lane;
    for (int ntg = 0; ntg < 64; ++ntg) {
        int d = ntg * 16 + low;
        float gqv = gqrow[d];
        float bnv = bn[d];
        cpart += tanh_c(bnv) * gqv;
        f32x4 acc[MT];
#pragma unroll
        for (int mt = 0; mt < MT; ++mt) acc[mt] = (f32x4){0.f, 0.f, 0.f, 0.f};
        const short8_t* bp = bb + (size_t)ntg * 512;
#pragma unroll
        for (int ks = 0; ks < 8; ++ks) {
            short8_t bf = bp[ks * 64];
#pragma unroll
            for (int mt = 0; mt < MT; ++mt)
                acc[mt] = __builtin_amdgcn_mfma_f32_16x16x32_bf16(af[mt][ks], bf, acc[mt], 0, 0, 0);
        }
#pragma unroll
        for (int mt = 0; mt < MT; ++mt)
#pragma unroll
            for (int jj = 0; jj < 4; ++jj)
                dacc[mt][jj] += tanh_c(acc[mt][jj] + bnv) * gqv;
    }

    // ---- reduce over the 16 low-lanes: dacc -> dots[slot = mt*16 + hi*4 + jj] ----
#pragma unroll
    for (int mt = 0; mt < MT; ++mt)
#pragma unroll
        for (int jj = 0; jj < 4; ++jj) {
            float v = dacc[mt][jj];
            v += __shfl_xor(v, 1);
            v += __shfl_xor(v, 2);
            v += __shfl_xor(v, 4);
            v += __shfl_xor(v, 8);
            dacc[mt][jj] = v;
        }
    float cq;
    {
        float cw = cpart;
#pragma unroll
        for (int off = 32; off > 0; off >>= 1) cw += __shfl_xor(cw, off);
        cq = 0.25f * cw;  // 4x hi-duplication of each d
    }

    // ---- wave-local softmax chain with analytic tail ----
    float mx = dacc[0][0];
#pragma unroll
    for (int mt = 0; mt < MT; ++mt)
#pragma unroll
        for (int jj = 0; jj < 4; ++jj) mx = fmaxf(mx, dacc[mt][jj]);
    mx = fmaxf(mx, __shfl_xor(mx, 16));
    mx = fmaxf(mx, __shfl_xor(mx, 32));
    if (TAIL > 0) mx = fmaxf(mx, cq);
    float ex[MT][4];
    float sm = 0.f;
#pragma unroll
    for (int mt = 0; mt < MT; ++mt)
#pragma unroll
        for (int jj = 0; jj < 4; ++jj) {
            ex[mt][jj] = __expf(dacc[mt][jj] - mx);
            sm += ex[mt][jj];
        }
    sm += __shfl_xor(sm, 16);
    sm += __shfl_xor(sm, 32);
    float ext = __expf(cq - mx);
    if (TAIL > 0) sm += (float)TAIL * ext;
    float pr = rel_prob[(size_t)q * RDIM + prob_idx[g]];
    float p10 = pr * 10.0f / sm;
    // logits in place
#pragma unroll
    for (int mt = 0; mt < MT; ++mt)
#pragma unroll
        for (int jj = 0; jj < 4; ++jj) ex[mt][jj] *= p10;
    float lgvt = ext * p10;
    float gm = ex[0][0];
#pragma unroll
    for (int mt = 0; mt < MT; ++mt)
#pragma unroll
        for (int jj = 0; jj < 4; ++jj) gm = fmaxf(gm, ex[mt][jj]);
    gm = fmaxf(gm, __shfl_xor(gm, 16));
    gm = fmaxf(gm, __shfl_xor(gm, 32));
    if (TAIL > 0) gm = fmaxf(gm, lgvt);
    float el[MT][4];
    float den = 0.f;
#pragma unroll
    for (int mt = 0; mt < MT; ++mt)
#pragma unroll
        for (int jj = 0; jj < 4; ++jj) {
            el[mt][jj] = __expf(ex[mt][jj] - gm);
            den += el[mt][jj];
        }
    den += __shfl_xor(den, 16);
    den += __shfl_xor(den, 32);
    if (TAIL > 0) den += (float)TAIL * __expf(lgvt - gm);
    if (lane == 0) {
        gden[g] = den;
        gmx[g] = gm;
    }

    // ---- lv[m] = el[slot(m)] * mask[m] via wave-private LDS ----
    float* lvarr = (float*)(ldsw + 8192);   // 64 floats
    float* mkarr = lvarr + 64;              // 64 floats
#pragma unroll
    for (int mt = 0; mt < MT; ++mt)
#pragma unroll
        for (int jj = 0; jj < 4; ++jj) lvarr[mt * 16 + hi * 4 + jj] = el[mt][jj];
    if (hi == 0) {
#pragma unroll
        for (int mt = 0; mt < MT; ++mt) {
            unsigned short s0 = (unsigned short)af[mt][0][0];  // tile[mt*16+low][e=0]
            mkarr[mt * 16 + low] = ((s0 & 0x7fffu) != 0) ? 1.0f : 0.0f;
        }
    }
    asm volatile("s_waitcnt lgkmcnt(0)" ::: "memory");
    float lvm[MT];
#pragma unroll
    for (int mt = 0; mt < MT; ++mt) lvm[mt] = lvarr[mt * 16 + low] * mkarr[mt * 16 + low];
    asm volatile("s_waitcnt lgkmcnt(0)" ::: "memory");

    // ---- weighted column sum from A-fragments in registers ----
    float ac[8][8];
#pragma unroll
    for (int ks = 0; ks < 8; ++ks)
#pragma unroll
        for (int j = 0; j < 8; ++j) ac[ks][j] = 0.f;
#pragma unroll
    for (int mt = 0; mt < MT; ++mt) {
        float lw = lvm[mt];
#pragma unroll
        for (int ks = 0; ks < 8; ++ks)
#pragma unroll
            for (int j = 0; j < 8; ++j)
                ac[ks][j] += bf2f((unsigned short)af[mt][ks][j]) * lw;
    }
    // reduce over rows (low lanes); e = ks*32 + hi*8 + j
#pragma unroll
    for (int ks = 0; ks < 8; ++ks)
#pragma unroll
        for (int j = 0; j < 8; ++j) {
            float a = ac[ks][j];
            a += __shfl_xor(a, 1);
            a += __shfl_xor(a, 2);
            a += __shfl_xor(a, 4);
            a += __shfl_xor(a, 8);
            ac[ks][j] = a;
        }
    // bounce through LDS for a coalesced float4 store
    float* vb = lvarr;  // 256 floats (reuse scratch; lv reads completed above)
#pragma unroll
    for (int ks = 0; ks < 8; ++ks)
#pragma unroll
        for (int j = 0; j < 8; ++j) vb[ks * 32 + hi * 8 + j] = ac[ks][j];
    asm volatile("s_waitcnt lgkmcnt(0)" ::: "memory");
    float4 ov = ((const float4*)vb)[lane];
    *(float4*)(gvec + (size_t)g * EDIM + lane * 4) = ov;
}

__global__ __launch_bounds__(256, 2) void phase1_mfma(
    const float* __restrict__ nodes, const short* __restrict__ wnpk,
    const float* __restrict__ bn, const float* __restrict__ gq,
    const float* __restrict__ rel_prob, const int* __restrict__ prob_idx,
    const int* __restrict__ glist, float* __restrict__ gvec,
    float* __restrict__ gden, float* __restrict__ gmx) {
    __shared__ char lds[4 * WREG];
    int w = threadIdx.x >> 6;
    int pk = glist[blockIdx.x * 4 + w];
    int g = pk & 0xFFFF;
    int mt = pk >> 16;
    int q = g >> 6;  // g / (K*N)
    char* ldsw = lds + w * WREG;
    switch (mt) {
        case 1: wave_body<1>(ldsw, g, q, nodes, wnpk, bn, gq, rel_prob, prob_idx, gvec, gden, gmx); break;
        case 2: wave_body<2>(ldsw, g, q, nodes, wnpk, bn, gq, rel_prob, prob_idx, gvec, gden, gmx); break;
        case 3: wave_body<3>(ldsw, g, q, nodes, wnpk, bn, gq, rel_prob, prob_idx, gvec, gden, gmx); break;
        default: wave_body<4>(ldsw, g, q, nodes, wnpk, bn, gq, rel_prob, prob_idx, gvec, gden, gmx); break;
    }
}

// ---------------- combine + out ----------------
__global__ __launch_bounds__(256) void combine_kernel(const float* __restrict__ gvec,
                                                      const float* __restrict__ gden,
                                                      const float* __restrict__ gmx,
                                                      float* __restrict__ memb) {
    int qk = blockIdx.x, t = threadIdx.x;
    __shared__ float sgm[NDIM], sden[NDIM];
    if (t < NDIM) {
        sgm[t] = gmx[qk * NDIM + t];
        sden[t] = gden[qk * NDIM + t];
    }
    __syncthreads();
    float gm = -INFINITY;
    for (int n = 0; n < NDIM; ++n) gm = fmaxf(gm, sgm[n]);
    float gs = 0.f;
    for (int n = 0; n < NDIM; ++n) gs += sden[n] * __expf(sgm[n] - gm);
    float me = 0.f;
    for (int n = 0; n < NDIM; ++n)
        me += gvec[(size_t)(qk * NDIM + n) * EDIM + t] * __expf(sgm[n] - gm);
    memb[(size_t)qk * EDIM + t] = me / (gs * (float)(NDIM * MDIM));
}

__global__ __launch_bounds__(256) void out_kernel(const float* __restrict__ memb,
                                                  const float* __restrict__ Wg,
                                                  const float* __restrict__ bg,
                                                  const int* __restrict__ gnn_idx,
                                                  float* __restrict__ out) {
    int q = blockIdx.x, t = threadIdx.x;
    __shared__ float pooled[EDIM];
    pooled[t] = 0.5f * (memb[(size_t)(q * 2 + 0) * EDIM + t] + memb[(size_t)(q * 2 + 1) * EDIM + t]);
    __syncthreads();
    float4 a = ((const float4*)bg)[t];
    const float4* Wg4 = (const float4*)Wg;
    for (int e = 0; e < EDIM; ++e) {
        float p = pooled[e];
        float4 w = Wg4[(size_t)e * (DDIM / 4) + t];
        a.x += p * w.x; a.y += p * w.y; a.z += p * w.z; a.w += p * w.w;
    }
    float4* op = (float4*)(out + (size_t)gnn_idx[q] * DDIM);
    float4 cur = op[t];
    cur.x += tanh_c(a.x);
    cur.y += tanh_c(a.y);
    cur.z += tanh_c(a.z);
    cur.w += tanh_c(a.w);
    op[t] = cur;
}

extern "C" void kernel_launch(void* const* d_in, const int* in_sizes, int n_in,
                              void* d_out, int out_size, void* d_ws, size_t ws_size,
                              hipStream_t stream) {
    const float* hs = (const float*)d_in[0];
    const float* nodes = (const float*)d_in[1];
    const int* prob_idx = (const int*)d_in[2];
    const int* gnn_idx = (const int*)d_in[3];
    const int* rel_idx = (const int*)d_in[4];
    const float* Wc = (const float*)d_in[5];
    const float* bc = (const float*)d_in[6];
    const float* Wq = (const float*)d_in[7];
    const float* bq = (const float*)d_in[8];
    const float* Wn = (const float*)d_in[9];
    const float* bn = (const float*)d_in[10];
    const float* Wg = (const float*)d_in[11];
    const float* bg = (const float*)d_in[12];
    float* out = (float*)d_out;
    float* ws = (float*)d_ws;

    // ws layout (floats): relprob[16384] | gq[65536] | gvec[1048576] | gden[4096]
    //   | gmax[4096] | memb[32768] | wnpk(bf16 = 131072 floats) | nvarr[4096]
    //   | bkt[8] | glist[4096]
    float* relprob = ws;
    float* gqbuf = ws + 16384;
    float* gvec = gqbuf + (size_t)QDIM * DDIM;
    float* gdenA = gvec + (size_t)GCOUNT * EDIM;
    float* gmaxA = gdenA + GCOUNT;
    float* membuf = gmaxA + GCOUNT;
    short* wnpk = (short*)(membuf + (size_t)QDIM * KDIM * EDIM);
    int* nvarr = (int*)(wnpk + (size_t)EDIM * DDIM);
    int* bkt = nvarr + GCOUNT;
    int* glist = bkt + 8;

    hipMemsetAsync(bkt, 0, 8 * sizeof(int), stream);
    prologue_kernel<<<3520, 256, 0, stream>>>(hs, out, Wn, wnpk, gnn_idx, Wq, bq,
                                              gqbuf, rel_idx, Wc, bc, relprob,
                                              nodes, nvarr, bkt);
    scatter_kernel<<<GCOUNT / 256, 256, 0, stream>>>(nvarr, bkt, glist);
    phase1_mfma<<<GCOUNT / 4, 256, 0, stream>>>(nodes, wnpk, bn, gqbuf, relprob,
                                                prob_idx, glist, gvec, gdenA, gmaxA);
    combine_kernel<<<QDIM * KDIM, 256, 0, stream>>>(gvec, gdenA, gmaxA, membuf);
    out_kernel<<<QDIM, 256, 0, stream>>>(membuf, Wg, bg, gnn_idx, out);
}